// Round 1
// baseline (673.049 us; speedup 1.0000x reference)
//
#include <hip/hip_runtime.h>
#include <hip/hip_bf16.h>
#include <stdint.h>

#define T_TOK 2048
#define HDIM  1024
#define IDIM  3584
#define NEXP  8
#define NROWS 4096   // T_TOK * TOP_K

typedef __attribute__((ext_vector_type(8))) short bf16x8;
typedef __attribute__((ext_vector_type(4))) float f32x4;
typedef __attribute__((ext_vector_type(4))) unsigned int u32x4;

__device__ __forceinline__ unsigned short f2bf(float f){
  union { float f; unsigned u; } v; v.f = f;
  unsigned r = v.u + 0x7FFFu + ((v.u >> 16) & 1u);   // round-to-nearest-even
  return (unsigned short)(r >> 16);
}

__device__ __forceinline__ u32x4 pack8(float4 lo, float4 hi){
  union { unsigned short s[8]; u32x4 v; } u;
  u.s[0]=f2bf(lo.x); u.s[1]=f2bf(lo.y); u.s[2]=f2bf(lo.z); u.s[3]=f2bf(lo.w);
  u.s[4]=f2bf(hi.x); u.s[5]=f2bf(hi.y); u.s[6]=f2bf(hi.z); u.s[7]=f2bf(hi.w);
  return u.v;
}

// ---------------- Kernel 1: RMSNorm + router ----------------
__global__ __launch_bounds__(256) void k_rms_router(
    const float* __restrict__ x, const float* __restrict__ rmsw,
    const float* __restrict__ gw, unsigned short* __restrict__ h_bf,
    int* __restrict__ topk_i, float* __restrict__ topk_w, int* __restrict__ count)
{
  const int t = blockIdx.x, tid = threadIdx.x;
  const int lane = tid & 63, wid = tid >> 6;
  float4 x4 = reinterpret_cast<const float4*>(x)[t*256 + tid];
  float ss = x4.x*x4.x + x4.y*x4.y + x4.z*x4.z + x4.w*x4.w;
  #pragma unroll
  for (int o = 32; o >= 1; o >>= 1) ss += __shfl_xor(ss, o);
  __shared__ float sred[4];
  __shared__ float slog[32];
  if (lane == 0) sred[wid] = ss;
  __syncthreads();
  float inv = rsqrtf((sred[0]+sred[1]+sred[2]+sred[3]) * (1.0f/HDIM) + 1e-6f);
  float4 w4 = reinterpret_cast<const float4*>(rmsw)[tid];
  float h0 = x4.x*inv*w4.x, h1 = x4.y*inv*w4.y, h2 = x4.z*inv*w4.z, h3 = x4.w*inv*w4.w;
  ushort4 hb; hb.x = f2bf(h0); hb.y = f2bf(h1); hb.z = f2bf(h2); hb.w = f2bf(h3);
  reinterpret_cast<ushort4*>(h_bf)[t*256 + tid] = hb;
  // router logits in fp32 (so top-k decisions match reference)
  #pragma unroll
  for (int e = 0; e < NEXP; e++){
    float4 g4 = reinterpret_cast<const float4*>(gw)[e*256 + tid];
    float v = h0*g4.x + h1*g4.y + h2*g4.z + h3*g4.w;
    #pragma unroll
    for (int o = 32; o >= 1; o >>= 1) v += __shfl_xor(v, o);
    if (lane == 0) slog[e*4 + wid] = v;
  }
  __syncthreads();
  if (tid == 0){
    float lg[NEXP];
    #pragma unroll
    for (int e = 0; e < NEXP; e++) lg[e] = slog[e*4]+slog[e*4+1]+slog[e*4+2]+slog[e*4+3];
    int i0 = 0;
    for (int e = 1; e < NEXP; e++) if (lg[e] > lg[i0]) i0 = e;   // ties -> lowest index
    int i1 = -1;
    for (int e = 0; e < NEXP; e++){ if (e == i0) continue; if (i1 < 0 || lg[e] > lg[i1]) i1 = e; }
    // softmax + top-2 renormalize == pairwise softmax over the two logits
    float m  = fmaxf(lg[i0], lg[i1]);
    float e0 = expf(lg[i0]-m), e1 = expf(lg[i1]-m);
    float s  = e0 + e1;
    topk_i[t*2] = i0; topk_i[t*2+1] = i1;
    topk_w[t*2] = e0/s; topk_w[t*2+1] = e1/s;
    atomicAdd(&count[i0], 1); atomicAdd(&count[i1], 1);
  }
}

// ---------------- Kernel 2: offsets ----------------
__global__ void k_scan(const int* __restrict__ count, int* __restrict__ offset){
  if (threadIdx.x == 0){
    int o = 0;
    for (int e = 0; e < NEXP; e++){ offset[e] = o; o += count[e]; }
  }
}

// ---------------- Kernel 3: scatter tokens to expert rows ----------------
__global__ __launch_bounds__(256) void k_scatter(
    const int* __restrict__ topk_i, const float* __restrict__ topk_w,
    const int* __restrict__ offset, int* __restrict__ cursor,
    int* __restrict__ token_of_row, float* __restrict__ wrow, int* __restrict__ slot_of)
{
  int t = blockIdx.x*256 + threadIdx.x;
  if (t >= T_TOK) return;
  #pragma unroll
  for (int k = 0; k < 2; k++){
    int e = topk_i[t*2+k];
    int pos = atomicAdd(&cursor[e], 1);
    int row = offset[e] + pos;
    token_of_row[row] = t;
    wrow[row] = topk_w[t*2+k];
    slot_of[t*2+k] = row;
  }
}

// ---------------- Kernel 4: fused w1/w3 GEMM + SwiGLU ----------------
// C tile: 128 rows x 64 cols. 4 waves (2x2), each 64x32. BK=64.
__global__ __launch_bounds__(256) void k_mlp_in(
    const unsigned short* __restrict__ h_bf, const float* __restrict__ w1,
    const float* __restrict__ w3, const int* __restrict__ token_of_row,
    const int* __restrict__ count, const int* __restrict__ offset,
    unsigned short* __restrict__ act)
{
  const int e = blockIdx.z;
  const int tile = blockIdx.x;
  const int cnt = count[e];
  if (tile * 128 >= cnt) return;
  const int off  = offset[e];
  const int row0 = off + tile*128;
  const int rend = off + cnt;
  const int col0 = blockIdx.y * 64;
  const int tid = threadIdx.x, lane = tid & 63, wid = tid >> 6;
  const int wave_r = wid >> 1, wave_c = wid & 1;

  __shared__ __align__(16) char sA [128*128];  // 128 rows x 64 bf16 (swizzled 16B slots)
  __shared__ __align__(16) char sB1[64*128];
  __shared__ __align__(16) char sB2[64*128];

  const int arow_base = tid >> 3;   // 0..31
  const int kseg = tid & 7;         // 16B slot within row
  int tokr[4];
  #pragma unroll
  for (int j = 0; j < 4; j++){
    int r = row0 + arow_base + 32*j;
    tokr[j] = token_of_row[min(r, NROWS-1)];
  }
  const float* w1base = w1 + (size_t)e*IDIM*HDIM + (size_t)col0*HDIM;
  const float* w3base = w3 + (size_t)e*IDIM*HDIM + (size_t)col0*HDIM;

  f32x4 acc_a[4][2], acc_g[4][2];
  #pragma unroll
  for (int m = 0; m < 4; m++)
    #pragma unroll
    for (int n = 0; n < 2; n++){
      acc_a[m][n] = (f32x4){0.f,0.f,0.f,0.f};
      acc_g[m][n] = (f32x4){0.f,0.f,0.f,0.f};
    }

  for (int kk = 0; kk < HDIM/64; kk++){
    if (kk) __syncthreads();
    // stage A (bf16 gather by token)
    #pragma unroll
    for (int j = 0; j < 4; j++){
      int r = arow_base + 32*j;
      u32x4 v = *reinterpret_cast<const u32x4*>(h_bf + (size_t)tokr[j]*HDIM + kk*64 + kseg*8);
      *reinterpret_cast<u32x4*>(sA + r*128 + ((kseg ^ (r&7))<<4)) = v;
    }
    // stage B1/B2 (fp32 -> bf16 on the fly)
    #pragma unroll
    for (int j = 0; j < 2; j++){
      int br = arow_base + 32*j;  // 0..63
      const float* p1 = w1base + (size_t)br*HDIM + kk*64 + kseg*8;
      const float* p3 = w3base + (size_t)br*HDIM + kk*64 + kseg*8;
      float4 lo1 = reinterpret_cast<const float4*>(p1)[0];
      float4 hi1 = reinterpret_cast<const float4*>(p1)[1];
      float4 lo3 = reinterpret_cast<const float4*>(p3)[0];
      float4 hi3 = reinterpret_cast<const float4*>(p3)[1];
      *reinterpret_cast<u32x4*>(sB1 + br*128 + ((kseg ^ (br&7))<<4)) = pack8(lo1, hi1);
      *reinterpret_cast<u32x4*>(sB2 + br*128 + ((kseg ^ (br&7))<<4)) = pack8(lo3, hi3);
    }
    __syncthreads();
    #pragma unroll
    for (int ki = 0; ki < 2; ki++){
      bf16x8 af[4];
      #pragma unroll
      for (int m = 0; m < 4; m++){
        int row = wave_r*64 + m*16 + (lane&15);
        int slot = ki*4 + (lane>>4);
        af[m] = *reinterpret_cast<const bf16x8*>(sA + row*128 + ((slot ^ (row&7))<<4));
      }
      #pragma unroll
      for (int n = 0; n < 2; n++){
        int col = wave_c*32 + n*16 + (lane&15);
        int slot = ki*4 + (lane>>4);
        bf16x8 b1 = *reinterpret_cast<const bf16x8*>(sB1 + col*128 + ((slot ^ (col&7))<<4));
        bf16x8 b2 = *reinterpret_cast<const bf16x8*>(sB2 + col*128 + ((slot ^ (col&7))<<4));
        #pragma unroll
        for (int m = 0; m < 4; m++){
          acc_a[m][n] = __builtin_amdgcn_mfma_f32_16x16x32_bf16(af[m], b1, acc_a[m][n], 0,0,0);
          acc_g[m][n] = __builtin_amdgcn_mfma_f32_16x16x32_bf16(af[m], b2, acc_g[m][n], 0,0,0);
        }
      }
    }
  }
  // epilogue: silu(a)*g -> bf16
  const int lcol = lane & 15, lrow4 = (lane >> 4) * 4;
  #pragma unroll
  for (int m = 0; m < 4; m++){
    #pragma unroll
    for (int n = 0; n < 2; n++){
      int gcol = col0 + wave_c*32 + n*16 + lcol;
      #pragma unroll
      for (int r = 0; r < 4; r++){
        int grow = row0 + wave_r*64 + m*16 + lrow4 + r;
        if (grow < rend){
          float a = acc_a[m][n][r], g = acc_g[m][n][r];
          float sig = 1.0f / (1.0f + __expf(-a));
          act[(size_t)grow*IDIM + gcol] = f2bf(a * sig * g);
        }
      }
    }
  }
}

// ---------------- Kernel 5: w2 GEMM ----------------
__global__ __launch_bounds__(256) void k_mlp_out(
    const unsigned short* __restrict__ act, const float* __restrict__ w2,
    const float* __restrict__ wrow, const int* __restrict__ count,
    const int* __restrict__ offset, float* __restrict__ eo)
{
  const int e = blockIdx.z, tile = blockIdx.x;
  const int cnt = count[e];
  if (tile*128 >= cnt) return;
  const int off = offset[e], row0 = off + tile*128, rend = off + cnt;
  const int col0 = blockIdx.y * 64;
  const int tid = threadIdx.x, lane = tid & 63, wid = tid >> 6;
  const int wave_r = wid >> 1, wave_c = wid & 1;

  __shared__ __align__(16) char sA[128*128];
  __shared__ __align__(16) char sB[64*128];

  const int arow_base = tid >> 3, kseg = tid & 7;
  size_t asrc[4];
  #pragma unroll
  for (int j = 0; j < 4; j++){
    int r = min(row0 + arow_base + 32*j, NROWS-1);
    asrc[j] = (size_t)r * IDIM;
  }
  const float* w2base = w2 + (size_t)e*HDIM*IDIM + (size_t)col0*IDIM;

  f32x4 acc[4][2];
  #pragma unroll
  for (int m = 0; m < 4; m++)
    #pragma unroll
    for (int n = 0; n < 2; n++) acc[m][n] = (f32x4){0.f,0.f,0.f,0.f};

  for (int kk = 0; kk < IDIM/64; kk++){
    if (kk) __syncthreads();
    #pragma unroll
    for (int j = 0; j < 4; j++){
      int r = arow_base + 32*j;
      u32x4 v = *reinterpret_cast<const u32x4*>(act + asrc[j] + kk*64 + kseg*8);
      *reinterpret_cast<u32x4*>(sA + r*128 + ((kseg ^ (r&7))<<4)) = v;
    }
    #pragma unroll
    for (int j = 0; j < 2; j++){
      int br = arow_base + 32*j;
      const float* p = w2base + (size_t)br*IDIM + kk*64 + kseg*8;
      float4 lo = reinterpret_cast<const float4*>(p)[0];
      float4 hi = reinterpret_cast<const float4*>(p)[1];
      *reinterpret_cast<u32x4*>(sB + br*128 + ((kseg ^ (br&7))<<4)) = pack8(lo, hi);
    }
    __syncthreads();
    #pragma unroll
    for (int ki = 0; ki < 2; ki++){
      bf16x8 af[4];
      #pragma unroll
      for (int m = 0; m < 4; m++){
        int row = wave_r*64 + m*16 + (lane&15);
        int slot = ki*4 + (lane>>4);
        af[m] = *reinterpret_cast<const bf16x8*>(sA + row*128 + ((slot ^ (row&7))<<4));
      }
      #pragma unroll
      for (int n = 0; n < 2; n++){
        int col = wave_c*32 + n*16 + (lane&15);
        int slot = ki*4 + (lane>>4);
        bf16x8 bf = *reinterpret_cast<const bf16x8*>(sB + col*128 + ((slot ^ (col&7))<<4));
        #pragma unroll
        for (int m = 0; m < 4; m++)
          acc[m][n] = __builtin_amdgcn_mfma_f32_16x16x32_bf16(af[m], bf, acc[m][n], 0,0,0);
      }
    }
  }
  const int lcol = lane & 15, lrow4 = (lane >> 4) * 4;
  #pragma unroll
  for (int m = 0; m < 4; m++){
    #pragma unroll
    for (int n = 0; n < 2; n++){
      int gcol = col0 + wave_c*32 + n*16 + lcol;
      #pragma unroll
      for (int r = 0; r < 4; r++){
        int grow = row0 + wave_r*64 + m*16 + lrow4 + r;
        if (grow < rend){
          eo[(size_t)grow*HDIM + gcol] = acc[m][n][r] * wrow[grow];
        }
      }
    }
  }
}

// ---------------- Kernel 6: combine + residual ----------------
__global__ __launch_bounds__(256) void k_combine(
    const float* __restrict__ x, const float* __restrict__ eo,
    const int* __restrict__ slot_of, float* __restrict__ out)
{
  const int t = blockIdx.x, tid = threadIdx.x;
  const int s0 = slot_of[t*2], s1 = slot_of[t*2+1];
  float4 xv = reinterpret_cast<const float4*>(x)[t*256 + tid];
  float4 a  = reinterpret_cast<const float4*>(eo)[s0*256 + tid];
  float4 b  = reinterpret_cast<const float4*>(eo)[s1*256 + tid];
  float4 ov;
  ov.x = xv.x + a.x + b.x;
  ov.y = xv.y + a.y + b.y;
  ov.z = xv.z + a.z + b.z;
  ov.w = xv.w + a.w + b.w;
  reinterpret_cast<float4*>(out)[t*256 + tid] = ov;
}

extern "C" void kernel_launch(void* const* d_in, const int* in_sizes, int n_in,
                              void* d_out, int out_size, void* d_ws, size_t ws_size,
                              hipStream_t stream)
{
  const float* x    = (const float*)d_in[0];
  const float* rmsw = (const float*)d_in[1];
  const float* gw   = (const float*)d_in[2];
  const float* w1   = (const float*)d_in[3];
  const float* w2   = (const float*)d_in[4];
  const float* w3   = (const float*)d_in[5];
  float* out = (float*)d_out;

  char* ws = (char*)d_ws;
  size_t o = 0;
  auto alloc = [&](size_t bytes) -> void* {
    void* p = ws + o;
    o += (bytes + 255) & ~(size_t)255;
    return p;
  };
  unsigned short* h_bf   = (unsigned short*)alloc((size_t)T_TOK*HDIM*2);
  int*   topk_i          = (int*)  alloc(T_TOK*2*4);
  float* topk_w          = (float*)alloc(T_TOK*2*4);
  int*   counters        = (int*)  alloc(64*4);   // count[8], cursor[8], offset[8]
  int*   token_of_row    = (int*)  alloc(NROWS*4);
  float* wrow            = (float*)alloc(NROWS*4);
  int*   slot_of         = (int*)  alloc(T_TOK*2*4);
  unsigned short* act    = (unsigned short*)alloc((size_t)NROWS*IDIM*2);
  float* eo              = (float*)alloc((size_t)NROWS*HDIM*4);
  int* count  = counters;
  int* cursor = counters + 8;
  int* offset = counters + 16;

  hipMemsetAsync(counters, 0, 64*4, stream);
  k_rms_router<<<T_TOK, 256, 0, stream>>>(x, rmsw, gw, h_bf, topk_i, topk_w, count);
  k_scan<<<1, 64, 0, stream>>>(count, offset);
  k_scatter<<<(T_TOK+255)/256, 256, 0, stream>>>(topk_i, topk_w, offset, cursor,
                                                 token_of_row, wrow, slot_of);
  // x = row tile (fastest) so concurrent blocks share the same weight tile in L2
  k_mlp_in <<<dim3(16, IDIM/64, NEXP), 256, 0, stream>>>(h_bf, w1, w3, token_of_row,
                                                         count, offset, act);
  k_mlp_out<<<dim3(16, HDIM/64, NEXP), 256, 0, stream>>>(act, w2, wrow, count, offset, eo);
  k_combine<<<T_TOK, 256, 0, stream>>>(x, eo, slot_of, out);
}

// Round 2
// 357.864 us; speedup vs baseline: 1.8807x; 1.8807x over previous
//
#include <hip/hip_runtime.h>
#include <hip/hip_bf16.h>
#include <stdint.h>

#define T_TOK 2048
#define HDIM  1024
#define IDIM  3584
#define NEXP  8
#define NROWS 4096   // T_TOK * TOP_K

typedef __attribute__((ext_vector_type(8))) short bf16x8;
typedef __attribute__((ext_vector_type(4))) float f32x4;
typedef __attribute__((ext_vector_type(4))) unsigned int u32x4;

__device__ __forceinline__ unsigned short f2bf(float f){
  union { float f; unsigned u; } v; v.f = f;
  unsigned r = v.u + 0x7FFFu + ((v.u >> 16) & 1u);   // round-to-nearest-even
  return (unsigned short)(r >> 16);
}

__device__ __forceinline__ u32x4 pack8(float4 lo, float4 hi){
  union { unsigned short s[8]; u32x4 v; } u;
  u.s[0]=f2bf(lo.x); u.s[1]=f2bf(lo.y); u.s[2]=f2bf(lo.z); u.s[3]=f2bf(lo.w);
  u.s[4]=f2bf(hi.x); u.s[5]=f2bf(hi.y); u.s[6]=f2bf(hi.z); u.s[7]=f2bf(hi.w);
  return u.v;
}

// ---------------- Kernel 1: RMSNorm + router ----------------
__global__ __launch_bounds__(256) void k_rms_router(
    const float* __restrict__ x, const float* __restrict__ rmsw,
    const float* __restrict__ gw, unsigned short* __restrict__ h_bf,
    int* __restrict__ topk_i, float* __restrict__ topk_w, int* __restrict__ count)
{
  const int t = blockIdx.x, tid = threadIdx.x;
  const int lane = tid & 63, wid = tid >> 6;
  float4 x4 = reinterpret_cast<const float4*>(x)[t*256 + tid];
  float ss = x4.x*x4.x + x4.y*x4.y + x4.z*x4.z + x4.w*x4.w;
  #pragma unroll
  for (int o = 32; o >= 1; o >>= 1) ss += __shfl_xor(ss, o);
  __shared__ float sred[4];
  __shared__ float slog[32];
  if (lane == 0) sred[wid] = ss;
  __syncthreads();
  float inv = rsqrtf((sred[0]+sred[1]+sred[2]+sred[3]) * (1.0f/HDIM) + 1e-6f);
  float4 w4 = reinterpret_cast<const float4*>(rmsw)[tid];
  float h0 = x4.x*inv*w4.x, h1 = x4.y*inv*w4.y, h2 = x4.z*inv*w4.z, h3 = x4.w*inv*w4.w;
  ushort4 hb; hb.x = f2bf(h0); hb.y = f2bf(h1); hb.z = f2bf(h2); hb.w = f2bf(h3);
  reinterpret_cast<ushort4*>(h_bf)[t*256 + tid] = hb;
  // router logits in fp32 (so top-k decisions match reference)
  #pragma unroll
  for (int e = 0; e < NEXP; e++){
    float4 g4 = reinterpret_cast<const float4*>(gw)[e*256 + tid];
    float v = h0*g4.x + h1*g4.y + h2*g4.z + h3*g4.w;
    #pragma unroll
    for (int o = 32; o >= 1; o >>= 1) v += __shfl_xor(v, o);
    if (lane == 0) slog[e*4 + wid] = v;
  }
  __syncthreads();
  if (tid == 0){
    float lg[NEXP];
    #pragma unroll
    for (int e = 0; e < NEXP; e++) lg[e] = slog[e*4]+slog[e*4+1]+slog[e*4+2]+slog[e*4+3];
    int i0 = 0;
    for (int e = 1; e < NEXP; e++) if (lg[e] > lg[i0]) i0 = e;   // ties -> lowest index
    int i1 = -1;
    for (int e = 0; e < NEXP; e++){ if (e == i0) continue; if (i1 < 0 || lg[e] > lg[i1]) i1 = e; }
    float m  = fmaxf(lg[i0], lg[i1]);
    float e0 = expf(lg[i0]-m), e1 = expf(lg[i1]-m);
    float s  = e0 + e1;
    topk_i[t*2] = i0; topk_i[t*2+1] = i1;
    topk_w[t*2] = e0/s; topk_w[t*2+1] = e1/s;
    atomicAdd(&count[i0], 1); atomicAdd(&count[i1], 1);
  }
}

// ---------------- Kernel 2: offsets ----------------
__global__ void k_scan(const int* __restrict__ count, int* __restrict__ offset){
  if (threadIdx.x == 0){
    int o = 0;
    for (int e = 0; e < NEXP; e++){ offset[e] = o; o += count[e]; }
  }
}

// ---------------- Kernel 3: scatter tokens to expert rows ----------------
__global__ __launch_bounds__(256) void k_scatter(
    const int* __restrict__ topk_i, const float* __restrict__ topk_w,
    const int* __restrict__ offset, int* __restrict__ cursor,
    int* __restrict__ token_of_row, float* __restrict__ wrow, int* __restrict__ slot_of)
{
  int t = blockIdx.x*256 + threadIdx.x;
  if (t >= T_TOK) return;
  #pragma unroll
  for (int k = 0; k < 2; k++){
    int e = topk_i[t*2+k];
    int pos = atomicAdd(&cursor[e], 1);
    int row = offset[e] + pos;
    token_of_row[row] = t;
    wrow[row] = topk_w[t*2+k];
    slot_of[t*2+k] = row;
  }
}

// ---------------- Kernel 4: fused w1/w3 GEMM + SwiGLU (2-phase pipelined) ----------------
// C tile: 128 rows x 64 cols. 4 waves (2x2), each 64x32. BK=64.
__global__ __launch_bounds__(256, 3) void k_mlp_in(
    const unsigned short* __restrict__ h_bf, const float* __restrict__ w1,
    const float* __restrict__ w3, const int* __restrict__ token_of_row,
    const int* __restrict__ count, const int* __restrict__ offset,
    unsigned short* __restrict__ act)
{
  // XCD-chunked remap: nwg = 16*56*8 = 7168, q = 896. Row tiles sharing a
  // weight panel become consecutive on the SAME XCD -> L2 reuse.
  int bx, by, bz;
  {
    int d = blockIdx.x + 16*(blockIdx.y + 56*blockIdx.z);
    int w = (d & 7)*896 + (d >> 3);
    bx = w & 15; int r = w >> 4; by = r % 56; bz = r / 56;
  }
  const int e = bz;
  const int tile = bx;
  const int cnt = count[e];
  if (tile * 128 >= cnt) return;
  const int off  = offset[e];
  const int row0 = off + tile*128;
  const int rend = off + cnt;
  const int col0 = by * 64;
  const int tid = threadIdx.x, lane = tid & 63, wid = tid >> 6;
  const int wave_r = wid >> 1, wave_c = wid & 1;

  __shared__ __align__(16) char sA [128*128];  // 128 rows x 64 bf16 (swizzled 16B slots)
  __shared__ __align__(16) char sB1[64*128];
  __shared__ __align__(16) char sB2[64*128];

  const int arow_base = tid >> 3;   // 0..31
  const int kseg = tid & 7;         // 16B slot within row
  const unsigned short* aptr[4];
  #pragma unroll
  for (int j = 0; j < 4; j++){
    int r = row0 + arow_base + 32*j;
    aptr[j] = h_bf + (size_t)token_of_row[min(r, NROWS-1)]*HDIM + kseg*8;
  }
  const float* w1base = w1 + (size_t)e*IDIM*HDIM + (size_t)col0*HDIM + (size_t)arow_base*HDIM + kseg*8;
  const float* w3base = w3 + (size_t)e*IDIM*HDIM + (size_t)col0*HDIM + (size_t)arow_base*HDIM + kseg*8;

  // prefetch registers
  u32x4  pa[4];
  float4 pb1[2][2], pb3[2][2];

  auto LOAD = [&](int kk){
    #pragma unroll
    for (int j = 0; j < 4; j++)
      pa[j] = *reinterpret_cast<const u32x4*>(aptr[j] + kk*64);
    #pragma unroll
    for (int j = 0; j < 2; j++){
      const float4* p1 = reinterpret_cast<const float4*>(w1base + (size_t)(32*j)*HDIM + kk*64);
      const float4* p3 = reinterpret_cast<const float4*>(w3base + (size_t)(32*j)*HDIM + kk*64);
      pb1[j][0] = p1[0]; pb1[j][1] = p1[1];
      pb3[j][0] = p3[0]; pb3[j][1] = p3[1];
    }
  };
  const int aswz = (kseg ^ (arow_base & 7)) << 4;   // 32*j doesn't change row&7
  auto STORE = [&](){
    #pragma unroll
    for (int j = 0; j < 4; j++)
      *reinterpret_cast<u32x4*>(sA + (arow_base + 32*j)*128 + aswz) = pa[j];
    #pragma unroll
    for (int j = 0; j < 2; j++){
      *reinterpret_cast<u32x4*>(sB1 + (arow_base + 32*j)*128 + aswz) = pack8(pb1[j][0], pb1[j][1]);
      *reinterpret_cast<u32x4*>(sB2 + (arow_base + 32*j)*128 + aswz) = pack8(pb3[j][0], pb3[j][1]);
    }
  };

  f32x4 acc_a[4][2], acc_g[4][2];
  #pragma unroll
  for (int m = 0; m < 4; m++)
    #pragma unroll
    for (int n = 0; n < 2; n++){
      acc_a[m][n] = (f32x4){0.f,0.f,0.f,0.f};
      acc_g[m][n] = (f32x4){0.f,0.f,0.f,0.f};
    }

  LOAD(0);
  for (int kk = 0; kk < HDIM/64; kk++){
    STORE();                          // regs -> LDS (vmcnt wait lands here)
    if (kk + 1 < HDIM/64) LOAD(kk+1); // next tile in flight across compute
    __syncthreads();
    #pragma unroll
    for (int ki = 0; ki < 2; ki++){
      bf16x8 af[4];
      #pragma unroll
      for (int m = 0; m < 4; m++){
        int row = wave_r*64 + m*16 + (lane&15);
        int slot = ki*4 + (lane>>4);
        af[m] = *reinterpret_cast<const bf16x8*>(sA + row*128 + ((slot ^ (row&7))<<4));
      }
      #pragma unroll
      for (int n = 0; n < 2; n++){
        int col = wave_c*32 + n*16 + (lane&15);
        int slot = ki*4 + (lane>>4);
        bf16x8 b1 = *reinterpret_cast<const bf16x8*>(sB1 + col*128 + ((slot ^ (col&7))<<4));
        bf16x8 b2 = *reinterpret_cast<const bf16x8*>(sB2 + col*128 + ((slot ^ (col&7))<<4));
        #pragma unroll
        for (int m = 0; m < 4; m++){
          acc_a[m][n] = __builtin_amdgcn_mfma_f32_16x16x32_bf16(af[m], b1, acc_a[m][n], 0,0,0);
          acc_g[m][n] = __builtin_amdgcn_mfma_f32_16x16x32_bf16(af[m], b2, acc_g[m][n], 0,0,0);
        }
      }
    }
    __syncthreads();
  }
  // epilogue: silu(a)*g -> bf16
  const int lcol = lane & 15, lrow4 = (lane >> 4) * 4;
  #pragma unroll
  for (int m = 0; m < 4; m++){
    #pragma unroll
    for (int n = 0; n < 2; n++){
      int gcol = col0 + wave_c*32 + n*16 + lcol;
      #pragma unroll
      for (int r = 0; r < 4; r++){
        int grow = row0 + wave_r*64 + m*16 + lrow4 + r;
        if (grow < rend){
          float a = acc_a[m][n][r], g = acc_g[m][n][r];
          float sig = 1.0f / (1.0f + __expf(-a));
          act[(size_t)grow*IDIM + gcol] = f2bf(a * sig * g);
        }
      }
    }
  }
}

// ---------------- Kernel 5: w2 GEMM (2-phase pipelined) ----------------
__global__ __launch_bounds__(256, 4) void k_mlp_out(
    const unsigned short* __restrict__ act, const float* __restrict__ w2,
    const float* __restrict__ wrow, const int* __restrict__ count,
    const int* __restrict__ offset, float* __restrict__ eo)
{
  // XCD-chunked remap: nwg = 16*16*8 = 2048, q = 256.
  int bx, by, bz;
  {
    int d = blockIdx.x + 16*(blockIdx.y + 16*blockIdx.z);
    int w = (d & 7)*256 + (d >> 3);
    bx = w & 15; int r = w >> 4; by = r & 15; bz = r >> 4;
  }
  const int e = bz, tile = bx;
  const int cnt = count[e];
  if (tile*128 >= cnt) return;
  const int off = offset[e], row0 = off + tile*128, rend = off + cnt;
  const int col0 = by * 64;
  const int tid = threadIdx.x, lane = tid & 63, wid = tid >> 6;
  const int wave_r = wid >> 1, wave_c = wid & 1;

  __shared__ __align__(16) char sA[128*128];
  __shared__ __align__(16) char sB[64*128];

  const int arow_base = tid >> 3, kseg = tid & 7;
  const unsigned short* aptr[4];
  #pragma unroll
  for (int j = 0; j < 4; j++){
    int r = min(row0 + arow_base + 32*j, NROWS-1);
    aptr[j] = act + (size_t)r * IDIM + kseg*8;
  }
  const float* w2base = w2 + (size_t)e*HDIM*IDIM + (size_t)col0*IDIM + (size_t)arow_base*IDIM + kseg*8;

  u32x4  pa[4];
  float4 pb[2][2];

  auto LOAD = [&](int kk){
    #pragma unroll
    for (int j = 0; j < 4; j++)
      pa[j] = *reinterpret_cast<const u32x4*>(aptr[j] + kk*64);
    #pragma unroll
    for (int j = 0; j < 2; j++){
      const float4* p = reinterpret_cast<const float4*>(w2base + (size_t)(32*j)*IDIM + kk*64);
      pb[j][0] = p[0]; pb[j][1] = p[1];
    }
  };
  const int aswz = (kseg ^ (arow_base & 7)) << 4;
  auto STORE = [&](){
    #pragma unroll
    for (int j = 0; j < 4; j++)
      *reinterpret_cast<u32x4*>(sA + (arow_base + 32*j)*128 + aswz) = pa[j];
    #pragma unroll
    for (int j = 0; j < 2; j++)
      *reinterpret_cast<u32x4*>(sB + (arow_base + 32*j)*128 + aswz) = pack8(pb[j][0], pb[j][1]);
  };

  f32x4 acc[4][2];
  #pragma unroll
  for (int m = 0; m < 4; m++)
    #pragma unroll
    for (int n = 0; n < 2; n++) acc[m][n] = (f32x4){0.f,0.f,0.f,0.f};

  LOAD(0);
  for (int kk = 0; kk < IDIM/64; kk++){
    STORE();
    if (kk + 1 < IDIM/64) LOAD(kk+1);
    __syncthreads();
    #pragma unroll
    for (int ki = 0; ki < 2; ki++){
      bf16x8 af[4];
      #pragma unroll
      for (int m = 0; m < 4; m++){
        int row = wave_r*64 + m*16 + (lane&15);
        int slot = ki*4 + (lane>>4);
        af[m] = *reinterpret_cast<const bf16x8*>(sA + row*128 + ((slot ^ (row&7))<<4));
      }
      #pragma unroll
      for (int n = 0; n < 2; n++){
        int col = wave_c*32 + n*16 + (lane&15);
        int slot = ki*4 + (lane>>4);
        bf16x8 bf = *reinterpret_cast<const bf16x8*>(sB + col*128 + ((slot ^ (col&7))<<4));
        #pragma unroll
        for (int m = 0; m < 4; m++)
          acc[m][n] = __builtin_amdgcn_mfma_f32_16x16x32_bf16(af[m], bf, acc[m][n], 0,0,0);
      }
    }
    __syncthreads();
  }
  const int lcol = lane & 15, lrow4 = (lane >> 4) * 4;
  #pragma unroll
  for (int m = 0; m < 4; m++){
    #pragma unroll
    for (int n = 0; n < 2; n++){
      int gcol = col0 + wave_c*32 + n*16 + lcol;
      #pragma unroll
      for (int r = 0; r < 4; r++){
        int grow = row0 + wave_r*64 + m*16 + lrow4 + r;
        if (grow < rend){
          eo[(size_t)grow*HDIM + gcol] = acc[m][n][r] * wrow[grow];
        }
      }
    }
  }
}

// ---------------- Kernel 6: combine + residual ----------------
__global__ __launch_bounds__(256) void k_combine(
    const float* __restrict__ x, const float* __restrict__ eo,
    const int* __restrict__ slot_of, float* __restrict__ out)
{
  const int t = blockIdx.x, tid = threadIdx.x;
  const int s0 = slot_of[t*2], s1 = slot_of[t*2+1];
  float4 xv = reinterpret_cast<const float4*>(x)[t*256 + tid];
  float4 a  = reinterpret_cast<const float4*>(eo)[s0*256 + tid];
  float4 b  = reinterpret_cast<const float4*>(eo)[s1*256 + tid];
  float4 ov;
  ov.x = xv.x + a.x + b.x;
  ov.y = xv.y + a.y + b.y;
  ov.z = xv.z + a.z + b.z;
  ov.w = xv.w + a.w + b.w;
  reinterpret_cast<float4*>(out)[t*256 + tid] = ov;
}

extern "C" void kernel_launch(void* const* d_in, const int* in_sizes, int n_in,
                              void* d_out, int out_size, void* d_ws, size_t ws_size,
                              hipStream_t stream)
{
  const float* x    = (const float*)d_in[0];
  const float* rmsw = (const float*)d_in[1];
  const float* gw   = (const float*)d_in[2];
  const float* w1   = (const float*)d_in[3];
  const float* w2   = (const float*)d_in[4];
  const float* w3   = (const float*)d_in[5];
  float* out = (float*)d_out;

  char* ws = (char*)d_ws;
  size_t o = 0;
  auto alloc = [&](size_t bytes) -> void* {
    void* p = ws + o;
    o += (bytes + 255) & ~(size_t)255;
    return p;
  };
  unsigned short* h_bf   = (unsigned short*)alloc((size_t)T_TOK*HDIM*2);
  int*   topk_i          = (int*)  alloc(T_TOK*2*4);
  float* topk_w          = (float*)alloc(T_TOK*2*4);
  int*   counters        = (int*)  alloc(64*4);   // count[8], cursor[8], offset[8]
  int*   token_of_row    = (int*)  alloc(NROWS*4);
  float* wrow            = (float*)alloc(NROWS*4);
  int*   slot_of         = (int*)  alloc(T_TOK*2*4);
  unsigned short* act    = (unsigned short*)alloc((size_t)NROWS*IDIM*2);
  float* eo              = (float*)alloc((size_t)NROWS*HDIM*4);
  int* count  = counters;
  int* cursor = counters + 8;
  int* offset = counters + 16;

  hipMemsetAsync(counters, 0, 64*4, stream);
  k_rms_router<<<T_TOK, 256, 0, stream>>>(x, rmsw, gw, h_bf, topk_i, topk_w, count);
  k_scan<<<1, 64, 0, stream>>>(count, offset);
  k_scatter<<<(T_TOK+255)/256, 256, 0, stream>>>(topk_i, topk_w, offset, cursor,
                                                 token_of_row, wrow, slot_of);
  k_mlp_in <<<dim3(16, IDIM/64, NEXP), 256, 0, stream>>>(h_bf, w1, w3, token_of_row,
                                                         count, offset, act);
  k_mlp_out<<<dim3(16, HDIM/64, NEXP), 256, 0, stream>>>(act, w2, wrow, count, offset, eo);
  k_combine<<<T_TOK, 256, 0, stream>>>(x, eo, slot_of, out);
}